// Round 7
// baseline (57477.130 us; speedup 1.0000x reference)
//
#include <hip/hip_runtime.h>
#include <hip/hip_fp16.h>

#define T_STEPS 2048
#define B_SZ 128
#define I_SZ 10
#define H_SZ 512

#define NGRP 8            // batch groups
#define GWG 4             // workgroups per group  (sync fan-in = 4)
#define NWG (NGRP * GWG)  // 32 workgroups x 1024 threads
#define BSLICE 16         // batch rows per group
#define WCOL 128          // hidden cols per wg
#define NTHR 1024

typedef _Float16 f16x8 __attribute__((ext_vector_type(8)));
typedef float f32x4 __attribute__((ext_vector_type(4)));
typedef float f32x2 __attribute__((ext_vector_type(2)));
typedef unsigned long long u64t;

// flags: u32[NGRP][16] (one 64B line per group, entry [wgin] used). Cleared
// every launch (poison/replay safety).
__global__ void clear_flags_kernel(unsigned* p) {
    if (threadIdx.x < NGRP * 16)
        __hip_atomic_store(p + threadIdx.x, 0u,
                           __ATOMIC_RELAXED, __HIP_MEMORY_SCOPE_AGENT);
}

// Persistent LSTM, R3-PROVEN sync protocol, low-degree topology:
//   8 independent batch-groups x 4 wgs. Per step, the 4 wgs of a group
//   exchange their 16x128 h-tiles through a double-buffered fp16 buffer
//   (relaxed agent-scope atomics = LLC-coherent), with one per-wg flag:
//   publish = h stores -> vmcnt(0) drain -> __syncthreads -> flag store;
//   consume = poll 4 flags -> workgroup acquire fence -> u64 h loads.
//   No cache-wide maintenance ops anywhere; placement-agnostic.
__global__ __launch_bounds__(NTHR, 1) void lstm_persistent(
    const float* __restrict__ x,     // [T,B,I]
    const float* __restrict__ hx,    // [B,H]
    const float* __restrict__ cx,    // [B,H]
    const float* __restrict__ W_ih,  // [4H,I]
    const float* __restrict__ W_hh,  // [4H,H]
    const float* __restrict__ b_ih,  // [4H]
    const float* __restrict__ b_hh,  // [4H]
    float* __restrict__ out,         // [3*B*H] = h, h, c
    unsigned* flags,                 // [NGRP][16]
    _Float16* hbuf)                  // [2][NGRP][BSLICE][H]
{
    __shared__ float lds_g[4 * WCOL][17];   // [gate*128+colL][row], padded

    const int wg   = blockIdx.x;
    const int g    = wg >> 2;          // batch group 0..7
    const int wgin = wg & 3;           // wg within group 0..3
    const int tid  = threadIdx.x;
    const int wid  = tid >> 6;         // wave 0..15
    const int lane = tid & 63;
    const int fr_col = lane & 15;
    const int fr_kg  = lane >> 4;      // 0..3

    // ---- this wave's two gate-column fragments (covers 32 of 512 gate-cols)
    //      gcL = wid*32 + f*16 + fr_col ; gate = gcL>>7 ; colL = gcL&127
    int   gcL[2], wr[2];
    #pragma unroll
    for (int f = 0; f < 2; ++f) {
        gcL[f] = wid * 32 + f * 16 + fr_col;
        wr[f]  = (gcL[f] >> 7) * H_SZ + wgin * WCOL + (gcL[f] & 127);
    }

    // ---- W_hh B-fragments: 2 frags x 16 K-chunks, fp16 register-resident
    f16x8 wf[2][16];
    #pragma unroll
    for (int f = 0; f < 2; ++f)
        #pragma unroll
        for (int c = 0; c < 16; ++c) {
            const float* p = W_hh + (size_t)wr[f] * H_SZ + c * 32 + fr_kg * 8;
            f16x8 w;
            #pragma unroll
            for (int e = 0; e < 8; ++e) w[e] = (_Float16)p[e];
            wf[f][c] = w;
        }

    // ---- W_ih rows + combined bias
    float wih[2][I_SZ], bias[2];
    #pragma unroll
    for (int f = 0; f < 2; ++f) {
        #pragma unroll
        for (int i = 0; i < I_SZ; ++i) wih[f][i] = W_ih[wr[f] * I_SZ + i];
        bias[f] = b_ih[wr[f]] + b_hh[wr[f]];
    }

    // ---- owned cells: wave wid owns batch row wid; lane owns col pair
    const int orow  = wid;                         // row in slice (0..15)
    const int ocol  = wgin * WCOL + 2 * lane;      // global hidden col (even)
    const int gbrow = g * BSLICE + orow;           // global batch row

    float c0 = cx[gbrow * H_SZ + ocol];
    float c1 = cx[gbrow * H_SZ + ocol + 1];
    float h0 = hx[gbrow * H_SZ + ocol];
    float h1 = hx[gbrow * H_SZ + ocol + 1];

    // ---- publish h(0) into buffer 0, drain, flag=1
    {
        _Float16* hb0 = hbuf + (size_t)g * (BSLICE * H_SZ);
        union { _Float16 hp[2]; unsigned u; } pk;
        pk.hp[0] = (_Float16)h0; pk.hp[1] = (_Float16)h1;
        __hip_atomic_store((unsigned*)(hb0 + orow * H_SZ + ocol), pk.u,
                           __ATOMIC_RELAXED, __HIP_MEMORY_SCOPE_AGENT);
    }
    asm volatile("s_waitcnt vmcnt(0)" ::: "memory");
    __syncthreads();
    if (tid == 0)
        __hip_atomic_store(flags + g * 16 + wgin, 1u,
                           __ATOMIC_RELAXED, __HIP_MEMORY_SCOPE_AGENT);

    #pragma unroll 1
    for (int t = 0; t < T_STEPS; ++t) {
        // -- x_t @ W_ih^T + bias (h-independent, pre-poll)
        f32x4 acc[2];
        #pragma unroll
        for (int r = 0; r < 4; ++r) {
            const int grow = g * BSLICE + fr_kg * 4 + r;
            const f32x2* xp = (const f32x2*)(x + ((size_t)t * B_SZ + grow) * I_SZ);
            const f32x2 a0 = xp[0], a1 = xp[1], a2 = xp[2], a3 = xp[3], a4 = xp[4];
            #pragma unroll
            for (int f = 0; f < 2; ++f) {
                float s = bias[f];
                s += a0.x*wih[f][0] + a0.y*wih[f][1] + a1.x*wih[f][2] + a1.y*wih[f][3]
                   + a2.x*wih[f][4] + a2.y*wih[f][5] + a3.x*wih[f][6] + a3.y*wih[f][7]
                   + a4.x*wih[f][8] + a4.y*wih[f][9];
                acc[f][r] = s;
            }
        }

        // -- poll the group's 4 flags (one cache line), then acquire (no cache op)
        {
            const unsigned tgt = (unsigned)(t + 1);
            const unsigned* fp = flags + g * 16 + (lane & 3);
            for (;;) {
                unsigned fv = __hip_atomic_load(fp, __ATOMIC_RELAXED,
                                                __HIP_MEMORY_SCOPE_AGENT);
                if (__all(fv >= tgt)) break;
                __builtin_amdgcn_s_sleep(2);
            }
            __builtin_amdgcn_fence(__ATOMIC_ACQUIRE, "workgroup");
        }

        // -- A-fragments: 16 K-chunks of the group's 16x512 fp16 h-slice
        //    (u64 relaxed agent loads, LLC-fresh, compiler-pipelined)
        const u64t* hb64 = (const u64t*)(hbuf + ((size_t)(t & 1) * NGRP + g)
                                                 * (BSLICE * H_SZ));
        const u64t* ap = hb64 + ((fr_col * H_SZ + fr_kg * 8) >> 2);
        #pragma unroll
        for (int c = 0; c < 16; ++c) {
            union { u64t q[2]; f16x8 v; } au;
            au.q[0] = __hip_atomic_load(ap + c * 8 + 0, __ATOMIC_RELAXED,
                                        __HIP_MEMORY_SCOPE_AGENT);
            au.q[1] = __hip_atomic_load(ap + c * 8 + 1, __ATOMIC_RELAXED,
                                        __HIP_MEMORY_SCOPE_AGENT);
            acc[0] = __builtin_amdgcn_mfma_f32_16x16x32_f16(au.v, wf[0][c], acc[0], 0, 0, 0);
            acc[1] = __builtin_amdgcn_mfma_f32_16x16x32_f16(au.v, wf[1][c], acc[1], 0, 0, 0);
        }

        // -- gate pre-activations -> LDS   (WAR vs prev step protected by barrier #2)
        #pragma unroll
        for (int f = 0; f < 2; ++f)
            #pragma unroll
            for (int r = 0; r < 4; ++r)
                lds_g[gcL[f]][fr_kg * 4 + r] = acc[f][r];
        __syncthreads();   // barrier #1

        // -- c/h update for 2 owned cells; publish h(t+1)
        {
            const int cl = 2 * lane;
            const float i0 = lds_g[0 * WCOL + cl][orow],     f0 = lds_g[1 * WCOL + cl][orow];
            const float g0 = lds_g[2 * WCOL + cl][orow],     o0 = lds_g[3 * WCOL + cl][orow];
            const float i1 = lds_g[0 * WCOL + cl + 1][orow], f1 = lds_g[1 * WCOL + cl + 1][orow];
            const float g1 = lds_g[2 * WCOL + cl + 1][orow], o1 = lds_g[3 * WCOL + cl + 1][orow];

            const float ig0 = 1.f / (1.f + __expf(-i0));
            const float fg0 = 1.f / (1.f + __expf(-f0));
            const float eg0 = __expf(-2.f * g0);
            const float tg0 = (1.f - eg0) / (1.f + eg0);
            const float og0 = 1.f / (1.f + __expf(-o0));
            const float ig1 = 1.f / (1.f + __expf(-i1));
            const float fg1 = 1.f / (1.f + __expf(-f1));
            const float eg1 = __expf(-2.f * g1);
            const float tg1 = (1.f - eg1) / (1.f + eg1);
            const float og1 = 1.f / (1.f + __expf(-o1));

            c0 = fg0 * c0 + ig0 * tg0;
            c1 = fg1 * c1 + ig1 * tg1;
            const float e0 = __expf(-2.f * c0), e1 = __expf(-2.f * c1);
            h0 = og0 * (1.f - e0) / (1.f + e0);
            h1 = og1 * (1.f - e1) / (1.f + e1);

            if (t < T_STEPS - 1) {
                _Float16* hbn = hbuf + ((size_t)((t + 1) & 1) * NGRP + g)
                                        * (BSLICE * H_SZ);
                union { _Float16 hp[2]; unsigned u; } pk;
                pk.hp[0] = (_Float16)h0; pk.hp[1] = (_Float16)h1;
                __hip_atomic_store((unsigned*)(hbn + orow * H_SZ + ocol), pk.u,
                                   __ATOMIC_RELAXED, __HIP_MEMORY_SCOPE_AGENT);
            }
        }

        // -- drain own stores, wg rendezvous, announce (R3-proven release)
        asm volatile("s_waitcnt vmcnt(0)" ::: "memory");
        __syncthreads();   // barrier #2
        if (tid == 0 && t < T_STEPS - 1)
            __hip_atomic_store(flags + g * 16 + wgin, (unsigned)(t + 2),
                               __ATOMIC_RELAXED, __HIP_MEMORY_SCOPE_AGENT);
    }

    // ---- outputs: (h, h, c), each [B,H] f32
    out[gbrow * H_SZ + ocol]                       = h0;
    out[gbrow * H_SZ + ocol + 1]                   = h1;
    out[B_SZ * H_SZ + gbrow * H_SZ + ocol]         = h0;
    out[B_SZ * H_SZ + gbrow * H_SZ + ocol + 1]     = h1;
    out[2 * B_SZ * H_SZ + gbrow * H_SZ + ocol]     = c0;
    out[2 * B_SZ * H_SZ + gbrow * H_SZ + ocol + 1] = c1;
}

extern "C" void kernel_launch(void* const* d_in, const int* in_sizes, int n_in,
                              void* d_out, int out_size, void* d_ws, size_t ws_size,
                              hipStream_t stream) {
    const float* x    = (const float*)d_in[0];
    const float* hx   = (const float*)d_in[1];
    const float* cx   = (const float*)d_in[2];
    const float* W_ih = (const float*)d_in[3];
    const float* W_hh = (const float*)d_in[4];
    const float* b_ih = (const float*)d_in[5];
    const float* b_hh = (const float*)d_in[6];
    float* out = (float*)d_out;

    // ws: [0,512) flags ; [1024, 1024+256K) fp16 h double-buffer
    char* ws = (char*)d_ws;
    unsigned* flags = (unsigned*)ws;
    _Float16* hbuf  = (_Float16*)(ws + 1024);

    clear_flags_kernel<<<1, 256, 0, stream>>>(flags);
    lstm_persistent<<<NWG, NTHR, 0, stream>>>(x, hx, cx, W_ih, W_hh, b_ih, b_hh,
                                              out, flags, hbuf);
}

// Round 8
// 7779.758 us; speedup vs baseline: 7.3880x; 7.3880x over previous
//
#include <hip/hip_runtime.h>
#include <hip/hip_fp16.h>

#define T_STEPS 2048
#define B_SZ 128
#define I_SZ 10
#define H_SZ 512

#define NGRP 8            // batch groups (16 rows each)
#define GWG 8             // wgs per group (sync fan-in = 8)
#define NWG (NGRP * GWG)  // 64 workgroups
#define BSLICE 16         // batch rows per group
#define WCOL 64           // hidden cols per wg
#define NTHR 512          // 8 waves; 2 waves/SIMD -> <=256 VGPR

typedef _Float16 f16x8 __attribute__((ext_vector_type(8)));
typedef float f32x4 __attribute__((ext_vector_type(4)));
typedef float f32x2 __attribute__((ext_vector_type(2)));
typedef unsigned u32x4 __attribute__((ext_vector_type(4)));

// flags: u32[NGRP][16] (one 64B line per group; entries [0..GWG) used).
// Cleared every launch (replay/poison safety).
__global__ void clear_flags_kernel(unsigned* p) {
    if (threadIdx.x < NGRP * 16)
        __hip_atomic_store(p + threadIdx.x, 0u,
                           __ATOMIC_RELAXED, __HIP_MEMORY_SCOPE_AGENT);
}

// Persistent LSTM. Topology: 8 independent batch-groups x 8 wgs; each wg owns
// 64 hidden cols (all 4 gates, full K) for its group's 16 batch rows.
// Sync protocol = R3-proven: publish h as u32 relaxed agent-scope stores
// (sc0 sc1, coherent at LLC) -> vmcnt(0) drain -> __syncthreads -> per-wg
// flag store; consume = wave0 polls the group's 8 flags -> barrier ->
// 16B-granule sc0sc1 staging loads into LDS -> all waves read fragments.
//
// Double-buffer safety: wg W stores h(t+1) into buf[(t+1)&1] only after its
// poll(t) saw all group flags >= t+1; wg V set flag t+1 only after B4 of
// step t-1, which follows V's staging-reads of buf[(t-1)&1] (same parity as
// (t+1)&1). So no wg still reads a buffer being overwritten.
__global__ __launch_bounds__(NTHR, 2) void lstm_persistent(
    const float* __restrict__ x,     // [T,B,I]
    const float* __restrict__ hx,    // [B,H]
    const float* __restrict__ cx,    // [B,H]
    const float* __restrict__ W_ih,  // [4H,I]
    const float* __restrict__ W_hh,  // [4H,H]
    const float* __restrict__ b_ih,  // [4H]
    const float* __restrict__ b_hh,  // [4H]
    float* __restrict__ out,         // [3*B*H] = h, h, c
    unsigned* flags,                 // [NGRP][16]
    _Float16* hbuf)                  // [2][NGRP][BSLICE][H]
{
    __shared__ _Float16 h_stage[BSLICE][520];   // +8 fp16 pad -> row stride 1040B
    __shared__ float lds_g[4 * WCOL][17];       // [gate*64+col][row], padded

    const int wg   = blockIdx.x;
    const int g    = wg >> 3;          // batch group 0..7
    const int wgin = wg & 7;           // wg within group 0..7
    const int tid  = threadIdx.x;
    const int wid  = tid >> 6;         // wave 0..7
    const int lane = tid & 63;
    const int fr_col = lane & 15;
    const int fr_kg  = lane >> 4;      // 0..3

    // ---- this wave's two gate-column fragments (wg covers 256 gate-cols)
    int gcL[2], wr[2];
    #pragma unroll
    for (int f = 0; f < 2; ++f) {
        gcL[f] = wid * 32 + f * 16 + fr_col;              // 0..255
        wr[f]  = (gcL[f] >> 6) * H_SZ + wgin * WCOL + (gcL[f] & 63);
    }

    // ---- W_hh B-fragments: 2 frags x 16 K-chunks, fp16 register-resident
    f16x8 wf[2][16];
    #pragma unroll
    for (int f = 0; f < 2; ++f)
        #pragma unroll
        for (int c = 0; c < 16; ++c) {
            const float* p = W_hh + (size_t)wr[f] * H_SZ + c * 32 + fr_kg * 8;
            f16x8 w;
            #pragma unroll
            for (int e = 0; e < 8; ++e) w[e] = (_Float16)p[e];
            wf[f][c] = w;
        }

    // ---- W_ih rows + combined bias
    float wih[2][I_SZ], bias[2];
    #pragma unroll
    for (int f = 0; f < 2; ++f) {
        #pragma unroll
        for (int i = 0; i < I_SZ; ++i) wih[f][i] = W_ih[wr[f] * I_SZ + i];
        bias[f] = b_ih[wr[f]] + b_hh[wr[f]];
    }

    // ---- owned cells: 2 adjacent per thread (16 rows x 64 cols per wg)
    const int orow  = tid >> 5;                    // 0..15
    const int ocol  = wgin * WCOL + 2 * (tid & 31);
    const int gbrow = g * BSLICE + orow;

    float c0 = cx[gbrow * H_SZ + ocol];
    float c1 = cx[gbrow * H_SZ + ocol + 1];
    float h0 = hx[gbrow * H_SZ + ocol];
    float h1 = hx[gbrow * H_SZ + ocol + 1];

    // ---- staging map: thread stages 32B of the slice (row, 32B col-block)
    const int srow  = tid & 15;
    const int scolb = tid >> 4;                    // 0..31

    // ---- publish h(0) into buffer 0, drain, flag=1
    {
        _Float16* hb0 = hbuf + (size_t)g * (BSLICE * H_SZ);
        union { _Float16 hp[2]; unsigned u; } pk;
        pk.hp[0] = (_Float16)h0; pk.hp[1] = (_Float16)h1;
        __hip_atomic_store((unsigned*)(hb0 + orow * H_SZ + ocol), pk.u,
                           __ATOMIC_RELAXED, __HIP_MEMORY_SCOPE_AGENT);
    }
    asm volatile("s_waitcnt vmcnt(0)" ::: "memory");
    __syncthreads();
    if (tid == 0)
        __hip_atomic_store(flags + g * 16 + wgin, 1u,
                           __ATOMIC_RELAXED, __HIP_MEMORY_SCOPE_AGENT);

    #pragma unroll 1
    for (int t = 0; t < T_STEPS; ++t) {
        // -- x_t @ W_ih^T + bias (h-independent, before the wait)
        f32x4 acc[2];
        #pragma unroll
        for (int r = 0; r < 4; ++r) {
            const int grow = g * BSLICE + fr_kg * 4 + r;
            const f32x2* xp = (const f32x2*)(x + ((size_t)t * B_SZ + grow) * I_SZ);
            const f32x2 a0 = xp[0], a1 = xp[1], a2 = xp[2], a3 = xp[3], a4 = xp[4];
            #pragma unroll
            for (int f = 0; f < 2; ++f) {
                float s = bias[f];
                s += a0.x*wih[f][0] + a0.y*wih[f][1] + a1.x*wih[f][2] + a1.y*wih[f][3]
                   + a2.x*wih[f][4] + a2.y*wih[f][5] + a3.x*wih[f][6] + a3.y*wih[f][7]
                   + a4.x*wih[f][8] + a4.y*wih[f][9];
                acc[f][r] = s;
            }
        }

        // -- wave 0 polls the group's 8 flags; everyone else waits at B1
        if (wid == 0) {
            const unsigned tgt = (unsigned)(t + 1);
            const unsigned* fp = flags + g * 16 + (lane & 7);
            for (;;) {
                unsigned fv = __hip_atomic_load(fp, __ATOMIC_RELAXED,
                                                __HIP_MEMORY_SCOPE_AGENT);
                if (__all(fv >= tgt)) break;
                __builtin_amdgcn_s_sleep(2);
            }
        }
        __syncthreads();   // B1: h(t) published (and prev staging reads done)

        // -- stage the group's 16x512 fp16 h-slice into LDS (16B sc0sc1 loads)
        {
            const _Float16* hb = hbuf + ((size_t)(t & 1) * NGRP + g) * (BSLICE * H_SZ);
            const char* sp = (const char*)hb + srow * 1024 + scolb * 32;
            u32x4 qa, qb;
            asm volatile("global_load_dwordx4 %0, %2, off sc0 sc1\n\t"
                         "global_load_dwordx4 %1, %2, off offset:16 sc0 sc1\n\t"
                         "s_waitcnt vmcnt(0)"
                         : "=&v"(qa), "=&v"(qb) : "v"(sp) : "memory");
            *(u32x4*)&h_stage[srow][scolb * 16]     = qa;
            *(u32x4*)&h_stage[srow][scolb * 16 + 8] = qb;
        }
        __syncthreads();   // B2: staging visible

        // -- 16 K-chunks: ds_read A-frag, 2 MFMAs each
        #pragma unroll
        for (int c = 0; c < 16; ++c) {
            const f16x8 a = *(const f16x8*)&h_stage[fr_col][c * 32 + fr_kg * 8];
            acc[0] = __builtin_amdgcn_mfma_f32_16x16x32_f16(a, wf[0][c], acc[0], 0, 0, 0);
            acc[1] = __builtin_amdgcn_mfma_f32_16x16x32_f16(a, wf[1][c], acc[1], 0, 0, 0);
        }

        // -- gate pre-activations -> LDS
        #pragma unroll
        for (int f = 0; f < 2; ++f)
            #pragma unroll
            for (int r = 0; r < 4; ++r)
                lds_g[gcL[f]][fr_kg * 4 + r] = acc[f][r];
        __syncthreads();   // B3: gates visible

        // -- c/h update for 2 owned cells; publish h(t+1)
        {
            const int cl = 2 * (tid & 31);
            const float i0 = lds_g[0 * WCOL + cl][orow],     f0 = lds_g[1 * WCOL + cl][orow];
            const float g0 = lds_g[2 * WCOL + cl][orow],     o0 = lds_g[3 * WCOL + cl][orow];
            const float i1 = lds_g[0 * WCOL + cl + 1][orow], f1 = lds_g[1 * WCOL + cl + 1][orow];
            const float g1 = lds_g[2 * WCOL + cl + 1][orow], o1 = lds_g[3 * WCOL + cl + 1][orow];

            const float ig0 = 1.f / (1.f + __expf(-i0));
            const float fg0 = 1.f / (1.f + __expf(-f0));
            const float eg0 = __expf(-2.f * g0);
            const float tg0 = (1.f - eg0) / (1.f + eg0);
            const float og0 = 1.f / (1.f + __expf(-o0));
            const float ig1 = 1.f / (1.f + __expf(-i1));
            const float fg1 = 1.f / (1.f + __expf(-f1));
            const float eg1 = __expf(-2.f * g1);
            const float tg1 = (1.f - eg1) / (1.f + eg1);
            const float og1 = 1.f / (1.f + __expf(-o1));

            c0 = fg0 * c0 + ig0 * tg0;
            c1 = fg1 * c1 + ig1 * tg1;
            const float e0 = __expf(-2.f * c0), e1 = __expf(-2.f * c1);
            h0 = og0 * (1.f - e0) / (1.f + e0);
            h1 = og1 * (1.f - e1) / (1.f + e1);

            if (t < T_STEPS - 1) {
                _Float16* hbn = hbuf + ((size_t)((t + 1) & 1) * NGRP + g)
                                        * (BSLICE * H_SZ);
                union { _Float16 hp[2]; unsigned u; } pk;
                pk.hp[0] = (_Float16)h0; pk.hp[1] = (_Float16)h1;
                __hip_atomic_store((unsigned*)(hbn + orow * H_SZ + ocol), pk.u,
                                   __ATOMIC_RELAXED, __HIP_MEMORY_SCOPE_AGENT);
            }
        }

        // -- drain own stores, wg rendezvous, announce
        asm volatile("s_waitcnt vmcnt(0)" ::: "memory");
        __syncthreads();   // B4
        if (tid == 0 && t < T_STEPS - 1)
            __hip_atomic_store(flags + g * 16 + wgin, (unsigned)(t + 2),
                               __ATOMIC_RELAXED, __HIP_MEMORY_SCOPE_AGENT);
    }

    // ---- outputs: (h, h, c), each [B,H] f32
    out[gbrow * H_SZ + ocol]                       = h0;
    out[gbrow * H_SZ + ocol + 1]                   = h1;
    out[B_SZ * H_SZ + gbrow * H_SZ + ocol]         = h0;
    out[B_SZ * H_SZ + gbrow * H_SZ + ocol + 1]     = h1;
    out[2 * B_SZ * H_SZ + gbrow * H_SZ + ocol]     = c0;
    out[2 * B_SZ * H_SZ + gbrow * H_SZ + ocol + 1] = c1;
}

extern "C" void kernel_launch(void* const* d_in, const int* in_sizes, int n_in,
                              void* d_out, int out_size, void* d_ws, size_t ws_size,
                              hipStream_t stream) {
    const float* x    = (const float*)d_in[0];
    const float* hx   = (const float*)d_in[1];
    const float* cx   = (const float*)d_in[2];
    const float* W_ih = (const float*)d_in[3];
    const float* W_hh = (const float*)d_in[4];
    const float* b_ih = (const float*)d_in[5];
    const float* b_hh = (const float*)d_in[6];
    float* out = (float*)d_out;

    // ws: [0,512) flags ; [1024, 1024+256K) fp16 h double-buffer
    char* ws = (char*)d_ws;
    unsigned* flags = (unsigned*)ws;
    _Float16* hbuf  = (_Float16*)(ws + 1024);

    clear_flags_kernel<<<1, 256, 0, stream>>>(flags);
    lstm_persistent<<<NWG, NTHR, 0, stream>>>(x, hx, cx, W_ih, W_hh, b_ih, b_hh,
                                              out, flags, hbuf);
}